// Round 3
// baseline (695.038 us; speedup 1.0000x reference)
//
#include <hip/hip_runtime.h>
#include <stdint.h>

#define B_    32
#define H_    8
#define KLEN_ 8192
#define D_    64
#define SPLIT 16                              // blocks per (b,h)
#define ROWS_PER_BLOCK (KLEN_ / SPLIT)        // 512
#define WAVES 4
#define TILES (ROWS_PER_BLOCK / (WAVES * 16)) // 8 tiles of 16 rows per wave

typedef __attribute__((ext_vector_type(8))) short short8;   // 8 bf16 (4 VGPRs)
typedef __attribute__((ext_vector_type(4))) float float4v;
typedef __attribute__((ext_vector_type(4))) unsigned int uint4v;

// pack two f32 -> bf16x2 dword (round-half-up; 2 adds + 1 v_perm_b32)
static __device__ inline unsigned int pack_bf16(float x0, float x1) {
    unsigned int a = __builtin_bit_cast(unsigned int, x0) + 0x8000u;
    unsigned int b = __builtin_bit_cast(unsigned int, x1) + 0x8000u;
    return __builtin_amdgcn_perm(b, a, 0x07060302u); // lo16=bf16(x0), hi16=bf16(x1)
}

static __device__ inline short8 pack8(const float4v& lo, const float4v& hi) {
    uint4v u;
    u[0] = pack_bf16(lo[0], lo[1]);
    u[1] = pack_bf16(lo[2], lo[3]);
    u[2] = pack_bf16(hi[0], hi[1]);
    u[3] = pack_bf16(hi[2], hi[3]);
    return __builtin_bit_cast(short8, u);
}

__global__ __launch_bounds__(256) void nais_score_kernel(
    const float* __restrict__ Q,    // [B,H,1,D]
    const float* __restrict__ K,    // [B,H,KLEN,D]
    const float* __restrict__ Wc,   // [H,2D,D]
    const float* __restrict__ Wo,   // [H,D,1]
    const float* __restrict__ bias, // [H,1,D]
    float* __restrict__ out)        // [B,H,KLEN]
{
    const int blk   = blockIdx.x;
    const int bh    = blk / SPLIT;
    const int split = blk % SPLIT;
    const int h     = bh % H_;
    const int tid   = threadIdx.x;
    const int lane  = tid & 63;
    const int wave  = tid >> 6;
    const int c     = lane & 15;   // fragment n/m index; output k-col
    const int q     = lane >> 4;   // quad

    __shared__ float s_qb[D_];
    __shared__ float s_wo[D_];

    // ---- q_proj[d] = bias[h,d] + sum_e Q[b,h,e] * Wc[h][e][d]  (fp32, exact) ----
    if (tid < D_) {
        const float* qv = Q + (size_t)bh * D_;
        const float* wq = Wc + (size_t)h * (2 * D_ * D_);
        float acc = bias[h * D_ + tid];
        #pragma unroll 8
        for (int e = 0; e < D_; ++e)
            acc += qv[e] * wq[e * D_ + tid];
        s_qb[tid] = acc;
        s_wo[tid] = Wo[h * D_ + tid];
    }
    __syncthreads();

    // ---- persistent Wk fragments (used as MFMA *A* operand = Wk^T) ----
    // lane (q,c) holds Wk[e = half*32 + q*8 + j][d = tt*16 + c], j=0..7
    // (A[m][k]: m=lane&15, k=q*8+j — identical per-lane data to the B layout)
    const float* wk = Wc + (size_t)h * (2 * D_ * D_) + D_ * D_;
    short8 wfrag[4][2];
    #pragma unroll
    for (int t = 0; t < 4; ++t) {
        const int d = t * 16 + c;
        #pragma unroll
        for (int half = 0; half < 2; ++half) {
            uint4v f;
            #pragma unroll
            for (int j2 = 0; j2 < 4; ++j2) {
                const int e = half * 32 + q * 8 + 2 * j2;
                f[j2] = pack_bf16(wk[(size_t)e * D_ + d], wk[(size_t)(e + 1) * D_ + d]);
            }
            wfrag[t][half] = __builtin_bit_cast(short8, f);
        }
    }

    // per-lane q_proj / Wo values for the transposed C layout:
    // lane (q,c), reg r of d-tile tt corresponds to d = tt*16 + q*4 + r
    float qbl[4][4], wol[4][4];
    #pragma unroll
    for (int t = 0; t < 4; ++t)
        #pragma unroll
        for (int r = 0; r < 4; ++r) {
            qbl[t][r] = s_qb[t * 16 + q * 4 + r];
            wol[t][r] = s_wo[t * 16 + q * 4 + r];
        }

    const float* Kb = K + (size_t)bh * KLEN_ * D_ + (size_t)split * ROWS_PER_BLOCK * D_;
    float*       ob = out + (size_t)bh * KLEN_ + (size_t)split * ROWS_PER_BLOCK;

    // direct per-lane loads: lane (q,c) reads row krow+c, f32 cols q*8.. (+4, +32, +36)
    #define ROW_PTR(t) (Kb + (size_t)((((t) * WAVES + wave) * 16) + c) * D_ + q * 8)

    float4v st[4];
    {
        const float* p = ROW_PTR(0);
        st[0] = *(const float4v*)(p);
        st[1] = *(const float4v*)(p + 4);
        st[2] = *(const float4v*)(p + 32);
        st[3] = *(const float4v*)(p + 36);
    }

    for (int t = 0; t < TILES; ++t) {
        // K^T fragments (MFMA *B* operand): lane holds B[k=half*32+q*8+j][n=c]
        short8 af0 = pack8(st[0], st[1]);   // e = 0..31 slice
        short8 af1 = pack8(st[2], st[3]);   // e = 32..63 slice

        if (t + 1 < TILES) {
            const float* p = ROW_PTR(t + 1);
            st[0] = *(const float4v*)(p);
            st[1] = *(const float4v*)(p + 4);
            st[2] = *(const float4v*)(p + 32);
            st[3] = *(const float4v*)(p + 36);
        }

        // hidden^T tiles: D[row = d_local][col = k_local]; reduce d mostly in-register
        float pr = 0.f;
        #pragma unroll
        for (int tt = 0; tt < 4; ++tt) {
            float4v acc = {0.f, 0.f, 0.f, 0.f};
            acc = __builtin_amdgcn_mfma_f32_16x16x32_bf16(wfrag[tt][0], af0, acc, 0, 0, 0);
            acc = __builtin_amdgcn_mfma_f32_16x16x32_bf16(wfrag[tt][1], af1, acc, 0, 0, 0);
            #pragma unroll
            for (int r = 0; r < 4; ++r) {
                float hv = fmaxf(acc[r] + qbl[tt][r], 0.f); // d = tt*16+q*4+r, k = krow+c
                pr = fmaf(hv, wol[tt][r], pr);
            }
        }

        // sum the 4 q-groups (lanes c, c+16, c+32, c+48): 2 shuffles total
        pr += __shfl_xor(pr, 16);
        pr += __shfl_xor(pr, 32);

        const int krow = (t * WAVES + wave) * 16;
        if (q == 0) ob[krow + c] = pr;   // one coalesced 64 B store, 16 lanes
    }
    #undef ROW_PTR
}

extern "C" void kernel_launch(void* const* d_in, const int* in_sizes, int n_in,
                              void* d_out, int out_size, void* d_ws, size_t ws_size,
                              hipStream_t stream) {
    const float* Q    = (const float*)d_in[0];
    const float* K    = (const float*)d_in[1];
    const float* Wc   = (const float*)d_in[2];
    const float* Wo   = (const float*)d_in[3];
    const float* bias = (const float*)d_in[4];
    float* out = (float*)d_out;

    dim3 grid(B_ * H_ * SPLIT);  // 4096 blocks
    dim3 block(256);
    nais_score_kernel<<<grid, block, 0, stream>>>(Q, K, Wc, Wo, bias, out);
}